// Round 6
// baseline (174.890 us; speedup 1.0000x reference)
//
#include <hip/hip_runtime.h>
#include <hip/hip_bf16.h>
#include <math.h>

// Problem constants
#define BT    96          // B*T = 8*12
#define NSEQ  512         // N
#define DMODEL 64         // D = K*d
#define RTOT  (BT * NSEQ) // 49152 rows

// Workspace layout (floats). Q/K/V and O are HEAD-MAJOR: [head][row][8],
// row = bt*512 + n. Offsets unchanged in size.
#define QOFF  0
#define KOFF  ((size_t)RTOT * DMODEL)
#define VOFF  ((size_t)2 * RTOT * DMODEL)
#define OOFF  ((size_t)3 * RTOT * DMODEL)
#define WOFF  ((size_t)4 * RTOT * DMODEL)   // W-fragment cache (128 KB)

#define HPLANE ((size_t)RTOT * 8)           // floats per head plane

// Guaranteed single-instruction 2^x / 1/x.
static __device__ inline float fast_exp2(float x) {
#if __has_builtin(__builtin_amdgcn_exp2f)
    return __builtin_amdgcn_exp2f(x);
#else
    float r; asm("v_exp_f32 %0, %1" : "=v"(r) : "v"(x)); return r;
#endif
}
static __device__ inline float fast_rcp(float x) {
#if __has_builtin(__builtin_amdgcn_rcpf)
    return __builtin_amdgcn_rcpf(x);
#else
    return 1.f / x;
#endif
}

typedef __attribute__((ext_vector_type(8)))  short short8;
typedef __attribute__((ext_vector_type(16))) float float16v;

static __device__ inline short8 as_s8(uint4 u) {
    union { uint4 u; short8 s; } x; x.u = u; return x.s;
}

static __device__ inline uint32_t bf162_bits(__hip_bfloat162 h) {
    union { __hip_bfloat162 h; uint32_t u; } x; x.h = h; return x.u;
}

// Split 8 fp32 into packed bf16 hi (RNE) + bf16 lo (exact residual, RNE).
static __device__ inline void split_pack8(const float* v, uint4* hi, uint4* lo) {
    uint32_t h[4], l[4];
    #pragma unroll
    for (int t = 0; t < 4; ++t) {
        float x0 = v[2 * t], x1 = v[2 * t + 1];
        uint32_t hw = bf162_bits(__float22bfloat162_rn(make_float2(x0, x1)));
        float h0 = __uint_as_float(hw << 16);
        float h1 = __uint_as_float(hw & 0xffff0000u);
        h[t] = hw;
        float l0 = x0 - h0;
        float l1 = x1 - h1;
        l[t] = bf162_bits(__float22bfloat162_rn(make_float2(l0, l1)));
    }
    *hi = make_uint4(h[0], h[1], h[2], h[3]);
    *lo = make_uint4(l[0], l[1], l[2], l[3]);
}

// ---------------------------------------------------------------------------
// Kernel 0: pre-split W7/8/9 (K=128) and W10/W11 (K=64) into bf16 hi/lo
// B-fragment layout. [0,3072) = W789; [3072,3584) = W10; [3584,4096) = W11.
// ---------------------------------------------------------------------------
__global__ __launch_bounds__(256) void wprep_kernel(
    const float* __restrict__ W7, const float* __restrict__ W8,
    const float* __restrict__ W9, const float* __restrict__ W10,
    const float* __restrict__ W11,
    uint4* __restrict__ WfH, uint4* __restrict__ WfL)
{
    const int e = blockIdx.x * 256 + threadIdx.x;   // 0..4095
    const float* W;
    int k0, col;
    if (e < 3072) {
        int n  = e & 31;
        int t  = (e >> 5) & 1;
        int hh = (e >> 6) & 1;
        int c  = (e >> 7) & 7;
        int w  = e >> 10;
        W = (w == 0) ? W7 : (w == 1) ? W8 : W9;
        k0 = c * 16 + hh * 8;
        col = t * 32 + n;
    } else {
        int pe = e - 3072;
        int n  = pe & 31;
        int t  = (pe >> 5) & 1;
        int hh = (pe >> 6) & 1;
        int c  = (pe >> 7) & 3;
        int m  = pe >> 9;
        W = (m == 0) ? W10 : W11;
        k0 = c * 16 + hh * 8;
        col = t * 32 + n;
    }
    float v[8];
    #pragma unroll
    for (int j = 0; j < 8; ++j) v[j] = W[(size_t)(k0 + j) * 64 + col];
    uint4 hi, lo;
    split_pack8(v, &hi, &lo);
    WfH[e] = hi;
    WfL[e] = lo;
}

// ---------------------------------------------------------------------------
// Kernel 1 (R14 = R12 revert): fused-W QKV, 6 waves/block, coalesced
// staging, DIRECT head-major stores (R13's LDS store round-trip cost ~5us).
// ---------------------------------------------------------------------------
__global__ __launch_bounds__(384) void qkv_kernel(
    const float* __restrict__ X, const float* __restrict__ STE,
    const uint4* __restrict__ WfH, const uint4* __restrict__ WfL,
    const float* __restrict__ b7, const float* __restrict__ b8,
    const float* __restrict__ b9,
    float* __restrict__ qkv)
{
    __shared__ float Xs[32][132];  // 16.9 KB raw [X|STE] rows (pad vs conflicts)
    __shared__ uint4 aH[512];      // 8 KB: A_hi frags, entry = c*64 + hh*32 + l31
    __shared__ uint4 aL[512];      // 8 KB: A_lo frags

    const int tid  = threadIdx.x;
    const int l31  = tid & 31;
    const int hh   = (tid >> 5) & 1;
    const int wave = tid >> 6;              // 0..5
    const int w    = wave >> 1;             // 0,1,2 -> W7,W8,W9
    const int tt   = wave & 1;              // column half
    const size_t blockrow = (size_t)blockIdx.x * 32;

    // Phase 1: coalesced raw stage. 1024 float4s: row = e>>5, seg = e&31.
    for (int e = tid; e < 1024; e += 384) {
        const int row = e >> 5;
        const int seg = e & 31;
        const float* src = (seg < 16) ? X : STE;
        const float4 v = *(const float4*)(src + (blockrow + row) * 64 + (seg & 15) * 4);
        float* dst = &Xs[row][seg * 4];
        dst[0] = v.x; dst[1] = v.y; dst[2] = v.z; dst[3] = v.w;
    }
    __syncthreads();

    // Phase 2: build split frags from LDS (split once, consumed by 6 waves).
    for (int e = tid; e < 512; e += 384) {
        const int el  = e & 31;
        const int ehh = (e >> 5) & 1;
        const int ec  = e >> 6;
        const float* hp = &Xs[el][ec * 16 + ehh * 8];
        float av[8];
        #pragma unroll
        for (int j = 0; j < 8; ++j) av[j] = hp[j];
        uint4 hi, lo;
        split_pack8(av, &hi, &lo);
        aH[e] = hi;
        aL[e] = lo;
    }
    __syncthreads();

    float16v accM, accC;
    #pragma unroll
    for (int i = 0; i < 16; ++i) { accM[i] = 0.f; accC[i] = 0.f; }

    #pragma unroll
    for (int c = 0; c < 8; ++c) {
        const uint4 ahi = aH[c * 64 + hh * 32 + l31];
        const uint4 alo = aL[c * 64 + hh * 32 + l31];
        const int ei = w * 1024 + c * 128 + hh * 64 + tt * 32 + l31;
        const uint4 bh = WfH[ei];
        const uint4 bl = WfL[ei];
        accM = __builtin_amdgcn_mfma_f32_32x32x16_bf16(
            as_s8(ahi), as_s8(bh), accM, 0, 0, 0);
        accC = __builtin_amdgcn_mfma_f32_32x32x16_bf16(
            as_s8(alo), as_s8(bh), accC, 0, 0, 0);
        accC = __builtin_amdgcn_mfma_f32_32x32x16_bf16(
            as_s8(ahi), as_s8(bl), accC, 0, 0, 0);
    }

    const float* bv = (w == 0) ? b7 : (w == 1) ? b8 : b9;
    // Head-major store: col = tt*32+l31 = head*8 + d.
    const int head = tt * 4 + (l31 >> 3);
    const int d    = l31 & 7;
    const int col  = tt * 32 + l31;
    float* obase = qkv + (size_t)w * ((size_t)RTOT * DMODEL) + (size_t)head * HPLANE;
    const float bias = bv[col];
    #pragma unroll
    for (int r = 0; r < 16; ++r) {
        const int rowC = (r & 3) + 8 * (r >> 2) + 4 * hh;
        obase[(blockrow + rowC) * 8 + d] =
            fmaxf(accM[r] + accC[r] + bias, 0.f);
    }
}

// ---------------------------------------------------------------------------
// Kernel 2 (R14): attention, 1536 blocks (qt-split, R13) + V staged through
// LDS: raw V coalesced into 16 KB LDS, frags gathered from LDS (was 4608
// scattered 4B GLOBAL loads per block). LDS 53.5 KB -> 3 blocks/CU.
// ---------------------------------------------------------------------------
__global__ __launch_bounds__(512, 4) void attn_kernel(
    const float* __restrict__ qkv, float* __restrict__ obuf)
{
    __shared__ uint4 ak1[16 * 32];    //  8.0 KB  k_hi
    __shared__ uint4 ak2p[16 * 33];   //  8.3 KB  k_lo | zero column
    __shared__ uint4 vfh[640];        // 10.0 KB  V_hi frags (+zero pad)
    __shared__ uint4 vfl[640];        // 10.0 KB  V_lo frags (+zero pad)
    __shared__ float vraw[4096];      // 16.0 KB  raw V rows [512][8]

    const int tid  = threadIdx.x;
    const int lane = tid & 63;
    const int l31  = lane & 31;
    const int hh   = lane >> 5;
    const int wv   = tid >> 6;               // 0..7
    const int bx   = blockIdx.x;
    const int qhalf = (bx >= 768) ? 1 : 0;
    const int pid  = bx - qhalf * 768;
    const int head = pid & 7;
    const int bt   = pid >> 3;
    const int qt   = qhalf * 8 + wv;         // this wave's q-tile

    // Head-major base: plane 'head', rows bt*512..bt*512+511, 8 floats/row.
    const size_t hb = (size_t)head * HPLANE + (size_t)bt * (NSEQ * 8);
    const float* Qp = qkv + QOFF + hb;
    const float* Kp = qkv + KOFF + hb;
    const float* Vp = qkv + VOFF + hb;

    const uint4 z4 = make_uint4(0, 0, 0, 0);

    // K staging: 512 threads, contiguous 32B rows.
    {
        const int k = tid;
        const float* kr = Kp + (size_t)k * 8;
        float kv[8];
        float4 a = *(const float4*)(kr);
        float4 b = *(const float4*)(kr + 4);
        kv[0] = a.x; kv[1] = a.y; kv[2] = a.z; kv[3] = a.w;
        kv[4] = b.x; kv[5] = b.y; kv[6] = b.z; kv[7] = b.w;
        uint4 hi, lo;
        split_pack8(kv, &hi, &lo);
        ak1[k] = hi;
        ak2p[(k >> 5) * 33 + (k & 31)] = lo;
    }
    if (tid < 16) ak2p[tid * 33 + 32] = z4;

    // Raw V staging: coalesced, 512 threads x 8 floats.
    {
        const float* vr = Vp + (size_t)tid * 8;
        const float4 a = *(const float4*)(vr);
        const float4 b = *(const float4*)(vr + 4);
        float* dst = &vraw[tid * 8];
        dst[0] = a.x; dst[1] = a.y; dst[2] = a.z; dst[3] = a.w;
        dst[4] = b.x; dst[5] = b.y; dst[6] = b.z; dst[7] = b.w;
    }
    __syncthreads();

    // V-frag build from LDS (gathers now hit LDS, not HBM).
    for (int e = tid; e < 640; e += 512) {
        if (e < 576) {
            int s  = e / 18;
            int r  = e % 18;
            int hv = r / 9;
            int n  = r % 9;
            float vv[8];
            #pragma unroll
            for (int j = 0; j < 8; ++j) {
                int key = 16 * s + ((j < 4) ? (4 * hv + j) : (8 + 4 * hv + (j - 4)));
                vv[j] = (n < 8) ? vraw[key * 8 + n] : 1.0f;
            }
            uint4 hi, lo;
            split_pack8(vv, &hi, &lo);
            vfh[e] = hi;
            vfl[e] = lo;
        } else {
            vfh[e] = z4;
            vfl[e] = z4;
        }
    }

    __syncthreads();

    const float C = 0.51012091684045906f;  // log2(e)/sqrt(8)
    const int idx2 = hh ? 32 : l31;        // zero column for hh=1 lanes

    float16v Z16;
    #pragma unroll
    for (int i = 0; i < 16; ++i) Z16[i] = 0.f;

    {
        const float* qp = Qp + (size_t)(qt * 32 + l31) * 8;
        float qv[8];
        {
            float4 a = *(const float4*)(qp);
            float4 b = *(const float4*)(qp + 4);
            qv[0] = a.x * C; qv[1] = a.y * C; qv[2] = a.z * C; qv[3] = a.w * C;
            qv[4] = b.x * C; qv[5] = b.y * C; qv[6] = b.z * C; qv[7] = b.w * C;
        }
        uint4 qhi, qlo;
        split_pack8(qv, &qhi, &qlo);
        const uint4 bq1 = hh ? qlo : qhi;
        const uint4 bq2 = qhi;

        float16v Oa = Z16, Ob = Z16;

        for (int c = 0; c < 16; ++c) {
            const uint4 a1 = ak1[c * 32 + l31];
            const uint4 a2 = ak2p[c * 33 + idx2];

            float16v S;
            S = __builtin_amdgcn_mfma_f32_32x32x16_bf16(as_s8(a1), as_s8(bq1), Z16, 0, 0, 0);
            S = __builtin_amdgcn_mfma_f32_32x32x16_bf16(as_s8(a2), as_s8(bq2), S, 0, 0, 0);

            #pragma unroll
            for (int i = 0; i < 16; ++i) S[i] = fast_exp2(S[i]);

            uint4 ph0, pl0, ph1, pl1;
            split_pack8((const float*)&S, &ph0, &pl0);
            split_pack8(((const float*)&S) + 8, &ph1, &pl1);

            // Per-half V frags: shorter liveness, same per-acc FP order.
            const int vi0 = (4 * c + hh) * 9;
            const uint4 bh0 = vfh[vi0 + l31];
            const uint4 bl0 = vfl[vi0 + l31];
            Oa = __builtin_amdgcn_mfma_f32_32x32x16_bf16(as_s8(ph0), as_s8(bh0), Oa, 0, 0, 0);
            Oa = __builtin_amdgcn_mfma_f32_32x32x16_bf16(as_s8(pl0), as_s8(bh0), Oa, 0, 0, 0);
            Oa = __builtin_amdgcn_mfma_f32_32x32x16_bf16(as_s8(ph0), as_s8(bl0), Oa, 0, 0, 0);

            const int vi1 = (4 * c + 2 + hh) * 9;
            const uint4 bh1 = vfh[vi1 + l31];
            const uint4 bl1 = vfl[vi1 + l31];
            Ob = __builtin_amdgcn_mfma_f32_32x32x16_bf16(as_s8(ph1), as_s8(bh1), Ob, 0, 0, 0);
            Ob = __builtin_amdgcn_mfma_f32_32x32x16_bf16(as_s8(pl1), as_s8(bh1), Ob, 0, 0, 0);
            Ob = __builtin_amdgcn_mfma_f32_32x32x16_bf16(as_s8(ph1), as_s8(bl1), Ob, 0, 0, 0);
        }

        #pragma unroll
        for (int r = 0; r < 16; ++r) {
            float ov = Oa[r] + Ob[r];
            float den = __uint_as_float(
                __builtin_amdgcn_ds_swizzle(__float_as_uint(ov), 0x100));
            float o = ov * fast_rcp(den);
            if (l31 < 8) {
                int row = (r & 3) + 8 * (r >> 2) + 4 * hh;
                obuf[hb + (size_t)(qt * 32 + row) * 8 + l31] = o;
            }
        }
    }
}

// ---------------------------------------------------------------------------
// Kernel 3 (R13, kept): fused projection; Ts padded to 84.
// ---------------------------------------------------------------------------
__global__ __launch_bounds__(128) void proj_kernel(
    const float* __restrict__ obuf,
    const uint4* __restrict__ WfH, const uint4* __restrict__ WfL,
    const float* __restrict__ b10, const float* __restrict__ b11,
    float* __restrict__ out)
{
    __shared__ float Ts[32][84];

    const int tid  = threadIdx.x;
    const int lane = tid & 63;
    const int l31  = lane & 31;
    const int hh   = lane >> 5;
    const int tw   = tid >> 6;               // 0/1: column half this wave owns
    const size_t row = (size_t)blockIdx.x * 32 + l31;
    const size_t blockrow = (size_t)blockIdx.x * 32;

    float16v accM, accC;
    #pragma unroll
    for (int i = 0; i < 16; ++i) { accM[i] = 0.f; accC[i] = 0.f; }

    #pragma unroll
    for (int c = 0; c < 4; ++c) {
        // A-frag cols c*16+hh*8..+7 = head plane 2c+hh, contiguous row.
        const float* ap = obuf + (size_t)(2 * c + hh) * HPLANE + row * 8;
        float av[8];
        {
            float4 a0 = *(const float4*)(ap);
            float4 a1 = *(const float4*)(ap + 4);
            av[0] = a0.x; av[1] = a0.y; av[2] = a0.z; av[3] = a0.w;
            av[4] = a1.x; av[5] = a1.y; av[6] = a1.z; av[7] = a1.w;
        }
        uint4 ahi, alo;
        split_pack8(av, &ahi, &alo);

        const int ei = 3072 + c * 128 + hh * 64 + tw * 32 + l31;   // W10
        const uint4 bh = WfH[ei];
        const uint4 bl = WfL[ei];
        accM = __builtin_amdgcn_mfma_f32_32x32x16_bf16(
            as_s8(ahi), as_s8(bh), accM, 0, 0, 0);
        accC = __builtin_amdgcn_mfma_f32_32x32x16_bf16(
            as_s8(alo), as_s8(bh), accC, 0, 0, 0);
        accC = __builtin_amdgcn_mfma_f32_32x32x16_bf16(
            as_s8(ahi), as_s8(bl), accC, 0, 0, 0);
    }

    {
        const int col = tw * 32 + l31;
        const float bias = b10[col];
        #pragma unroll
        for (int r = 0; r < 16; ++r) {
            const int rowC = (r & 3) + 8 * (r >> 2) + 4 * hh;
            Ts[rowC][col] = fmaxf(accM[r] + accC[r] + bias, 0.f);
        }
    }
    __syncthreads();

    #pragma unroll
    for (int i = 0; i < 16; ++i) { accM[i] = 0.f; accC[i] = 0.f; }

    #pragma unroll
    for (int c = 0; c < 4; ++c) {
        const float* ap = &Ts[l31][c * 16 + hh * 8];
        float av[8];
        {
            float4 a0 = *(const float4*)(ap);
            float4 a1 = *(const float4*)(ap + 4);
            av[0] = a0.x; av[1] = a0.y; av[2] = a0.z; av[3] = a0.w;
            av[4] = a1.x; av[5] = a1.y; av[6] = a1.z; av[7] = a1.w;
        }
        uint4 ahi, alo;
        split_pack8(av, &ahi, &alo);

        const int ei = 3584 + c * 128 + hh * 64 + tw * 32 + l31;   // W11
        const uint4 bh = WfH[ei];
        const uint4 bl = WfL[ei];
        accM = __builtin_amdgcn_mfma_f32_32x32x16_bf16(
            as_s8(ahi), as_s8(bh), accM, 0, 0, 0);
        accC = __builtin_amdgcn_mfma_f32_32x32x16_bf16(
            as_s8(alo), as_s8(bh), accC, 0, 0, 0);
        accC = __builtin_amdgcn_mfma_f32_32x32x16_bf16(
            as_s8(ahi), as_s8(bl), accC, 0, 0, 0);
    }

    {
        const int col = tw * 32 + l31;
        const float bias = b11[col];
        #pragma unroll
        for (int r = 0; r < 16; ++r) {
            const int rowC = (r & 3) + 8 * (r >> 2) + 4 * hh;
            out[(blockrow + rowC) * 64 + col] = accM[r] + accC[r] + bias;
        }
    }
}

// ---------------------------------------------------------------------------
extern "C" void kernel_launch(void* const* d_in, const int* in_sizes, int n_in,
                              void* d_out, int out_size, void* d_ws, size_t ws_size,
                              hipStream_t stream)
{
    const float* X   = (const float*)d_in[0];
    const float* STE = (const float*)d_in[1];
    const float* W7  = (const float*)d_in[2];
    const float* b7  = (const float*)d_in[3];
    const float* W8  = (const float*)d_in[4];
    const float* b8  = (const float*)d_in[5];
    const float* W9  = (const float*)d_in[6];
    const float* b9  = (const float*)d_in[7];
    const float* W10 = (const float*)d_in[8];
    const float* b10 = (const float*)d_in[9];
    const float* W11 = (const float*)d_in[10];
    const float* b11 = (const float*)d_in[11];

    float* ws  = (float*)d_ws;   // Q | K | V | O | Wf
    float* out = (float*)d_out;

    uint4* WfH = (uint4*)(ws + WOFF);
    uint4* WfL = WfH + 4096;

    wprep_kernel<<<dim3(16), 256, 0, stream>>>(W7, W8, W9, W10, W11, WfH, WfL);
    qkv_kernel<<<dim3(RTOT / 32), 384, 0, stream>>>(X, STE, WfH, WfL, b7, b8, b9, ws);
    attn_kernel<<<dim3(BT * 8 * 2), 512, 0, stream>>>(ws, ws + OOFF);
    proj_kernel<<<dim3(RTOT / 32), 128, 0, stream>>>(ws + OOFF, WfH, WfL, b10, b11, out);
}

// Round 8
// 173.527 us; speedup vs baseline: 1.0079x; 1.0079x over previous
//
#include <hip/hip_runtime.h>
#include <hip/hip_bf16.h>
#include <math.h>

// Problem constants
#define BT    96          // B*T = 8*12
#define NSEQ  512         // N
#define DMODEL 64         // D = K*d
#define RTOT  (BT * NSEQ) // 49152 rows

// Workspace layout (floats). Q/K/V and O are HEAD-MAJOR: [head][row][8],
// row = bt*512 + n. Offsets unchanged in size.
#define QOFF  0
#define KOFF  ((size_t)RTOT * DMODEL)
#define VOFF  ((size_t)2 * RTOT * DMODEL)
#define OOFF  ((size_t)3 * RTOT * DMODEL)
#define WOFF  ((size_t)4 * RTOT * DMODEL)   // W-fragment cache (128 KB)

#define HPLANE ((size_t)RTOT * 8)           // floats per head plane

// Guaranteed single-instruction 2^x / 1/x.
static __device__ inline float fast_exp2(float x) {
#if __has_builtin(__builtin_amdgcn_exp2f)
    return __builtin_amdgcn_exp2f(x);
#else
    float r; asm("v_exp_f32 %0, %1" : "=v"(r) : "v"(x)); return r;
#endif
}
static __device__ inline float fast_rcp(float x) {
#if __has_builtin(__builtin_amdgcn_rcpf)
    return __builtin_amdgcn_rcpf(x);
#else
    return 1.f / x;
#endif
}

typedef __attribute__((ext_vector_type(8)))  short short8;
typedef __attribute__((ext_vector_type(16))) float float16v;

static __device__ inline short8 as_s8(uint4 u) {
    union { uint4 u; short8 s; } x; x.u = u; return x.s;
}

static __device__ inline uint32_t bf162_bits(__hip_bfloat162 h) {
    union { __hip_bfloat162 h; uint32_t u; } x; x.h = h; return x.u;
}

// Split 8 fp32 into packed bf16 hi (RNE) + bf16 lo (exact residual, RNE).
static __device__ inline void split_pack8(const float* v, uint4* hi, uint4* lo) {
    uint32_t h[4], l[4];
    #pragma unroll
    for (int t = 0; t < 4; ++t) {
        float x0 = v[2 * t], x1 = v[2 * t + 1];
        uint32_t hw = bf162_bits(__float22bfloat162_rn(make_float2(x0, x1)));
        float h0 = __uint_as_float(hw << 16);
        float h1 = __uint_as_float(hw & 0xffff0000u);
        h[t] = hw;
        float l0 = x0 - h0;
        float l1 = x1 - h1;
        l[t] = bf162_bits(__float22bfloat162_rn(make_float2(l0, l1)));
    }
    *hi = make_uint4(h[0], h[1], h[2], h[3]);
    *lo = make_uint4(l[0], l[1], l[2], l[3]);
}

// ---------------------------------------------------------------------------
// Kernel 0: pre-split W7/8/9 (K=128) and W10/W11 (K=64) into bf16 hi/lo
// B-fragment layout. [0,3072) = W789; [3072,3584) = W10; [3584,4096) = W11.
// ---------------------------------------------------------------------------
__global__ __launch_bounds__(256) void wprep_kernel(
    const float* __restrict__ W7, const float* __restrict__ W8,
    const float* __restrict__ W9, const float* __restrict__ W10,
    const float* __restrict__ W11,
    uint4* __restrict__ WfH, uint4* __restrict__ WfL)
{
    const int e = blockIdx.x * 256 + threadIdx.x;   // 0..4095
    const float* W;
    int k0, col;
    if (e < 3072) {
        int n  = e & 31;
        int t  = (e >> 5) & 1;
        int hh = (e >> 6) & 1;
        int c  = (e >> 7) & 7;
        int w  = e >> 10;
        W = (w == 0) ? W7 : (w == 1) ? W8 : W9;
        k0 = c * 16 + hh * 8;
        col = t * 32 + n;
    } else {
        int pe = e - 3072;
        int n  = pe & 31;
        int t  = (pe >> 5) & 1;
        int hh = (pe >> 6) & 1;
        int c  = (pe >> 7) & 3;
        int m  = pe >> 9;
        W = (m == 0) ? W10 : W11;
        k0 = c * 16 + hh * 8;
        col = t * 32 + n;
    }
    float v[8];
    #pragma unroll
    for (int j = 0; j < 8; ++j) v[j] = W[(size_t)(k0 + j) * 64 + col];
    uint4 hi, lo;
    split_pack8(v, &hi, &lo);
    WfH[e] = hi;
    WfL[e] = lo;
}

// ---------------------------------------------------------------------------
// Kernel 1 (R14, kept): fused-W QKV, 6 waves/block, coalesced staging,
// direct head-major stores.
// ---------------------------------------------------------------------------
__global__ __launch_bounds__(384) void qkv_kernel(
    const float* __restrict__ X, const float* __restrict__ STE,
    const uint4* __restrict__ WfH, const uint4* __restrict__ WfL,
    const float* __restrict__ b7, const float* __restrict__ b8,
    const float* __restrict__ b9,
    float* __restrict__ qkv)
{
    __shared__ float Xs[32][132];  // 16.9 KB raw [X|STE] rows (pad vs conflicts)
    __shared__ uint4 aH[512];      // 8 KB: A_hi frags, entry = c*64 + hh*32 + l31
    __shared__ uint4 aL[512];      // 8 KB: A_lo frags

    const int tid  = threadIdx.x;
    const int l31  = tid & 31;
    const int hh   = (tid >> 5) & 1;
    const int wave = tid >> 6;              // 0..5
    const int w    = wave >> 1;             // 0,1,2 -> W7,W8,W9
    const int tt   = wave & 1;              // column half
    const size_t blockrow = (size_t)blockIdx.x * 32;

    // Phase 1: coalesced raw stage. 1024 float4s: row = e>>5, seg = e&31.
    for (int e = tid; e < 1024; e += 384) {
        const int row = e >> 5;
        const int seg = e & 31;
        const float* src = (seg < 16) ? X : STE;
        const float4 v = *(const float4*)(src + (blockrow + row) * 64 + (seg & 15) * 4);
        float* dst = &Xs[row][seg * 4];
        dst[0] = v.x; dst[1] = v.y; dst[2] = v.z; dst[3] = v.w;
    }
    __syncthreads();

    // Phase 2: build split frags from LDS (split once, consumed by 6 waves).
    for (int e = tid; e < 512; e += 384) {
        const int el  = e & 31;
        const int ehh = (e >> 5) & 1;
        const int ec  = e >> 6;
        const float* hp = &Xs[el][ec * 16 + ehh * 8];
        float av[8];
        #pragma unroll
        for (int j = 0; j < 8; ++j) av[j] = hp[j];
        uint4 hi, lo;
        split_pack8(av, &hi, &lo);
        aH[e] = hi;
        aL[e] = lo;
    }
    __syncthreads();

    float16v accM, accC;
    #pragma unroll
    for (int i = 0; i < 16; ++i) { accM[i] = 0.f; accC[i] = 0.f; }

    #pragma unroll
    for (int c = 0; c < 8; ++c) {
        const uint4 ahi = aH[c * 64 + hh * 32 + l31];
        const uint4 alo = aL[c * 64 + hh * 32 + l31];
        const int ei = w * 1024 + c * 128 + hh * 64 + tt * 32 + l31;
        const uint4 bh = WfH[ei];
        const uint4 bl = WfL[ei];
        accM = __builtin_amdgcn_mfma_f32_32x32x16_bf16(
            as_s8(ahi), as_s8(bh), accM, 0, 0, 0);
        accC = __builtin_amdgcn_mfma_f32_32x32x16_bf16(
            as_s8(alo), as_s8(bh), accC, 0, 0, 0);
        accC = __builtin_amdgcn_mfma_f32_32x32x16_bf16(
            as_s8(ahi), as_s8(bl), accC, 0, 0, 0);
    }

    const float* bv = (w == 0) ? b7 : (w == 1) ? b8 : b9;
    // Head-major store: col = tt*32+l31 = head*8 + d.
    const int head = tt * 4 + (l31 >> 3);
    const int d    = l31 & 7;
    const int col  = tt * 32 + l31;
    float* obase = qkv + (size_t)w * ((size_t)RTOT * DMODEL) + (size_t)head * HPLANE;
    const float bias = bv[col];
    #pragma unroll
    for (int r = 0; r < 16; ++r) {
        const int rowC = (r & 3) + 8 * (r >> 2) + 4 * hh;
        obase[(blockrow + rowC) * 8 + d] =
            fmaxf(accM[r] + accC[r] + bias, 0.f);
    }
}

// ---------------------------------------------------------------------------
// Kernel 2 (R15): attention, 768 blocks x 1024 threads (16 waves), ONE qt
// per wave. Staging paid once per (bt,head). V-gather back to GLOBAL (R6's
// LDS route: 860K bank conflicts, +5us). Single O accumulator (was Oa+Ob):
// -16 AGPRs -> combined regfile ~88/wave -> 5 waves/SIMD cap (was 4).
// ---------------------------------------------------------------------------
__global__ __launch_bounds__(1024) void attn_kernel(
    const float* __restrict__ qkv, float* __restrict__ obuf)
{
    __shared__ uint4 ak1[16 * 32];    //  8.0 KB  k_hi
    __shared__ uint4 ak2p[16 * 33];   //  8.3 KB  k_lo | zero column
    __shared__ uint4 vfh[640];        // 10.0 KB  V_hi frags (+zero pad)
    __shared__ uint4 vfl[640];        // 10.0 KB  V_lo frags (+zero pad)

    const int tid  = threadIdx.x;
    const int lane = tid & 63;
    const int l31  = lane & 31;
    const int hh   = lane >> 5;
    const int qt   = tid >> 6;               // 0..15: this wave's q-tile
    const int head = blockIdx.x & 7;
    const int bt   = blockIdx.x >> 3;

    // Head-major base: plane 'head', rows bt*512..bt*512+511, 8 floats/row.
    const size_t hb = (size_t)head * HPLANE + (size_t)bt * (NSEQ * 8);
    const float* Qp = qkv + QOFF + hb;
    const float* Kp = qkv + KOFF + hb;
    const float* Vp = qkv + VOFF + hb;

    const uint4 z4 = make_uint4(0, 0, 0, 0);

    // K staging: threads 0..511, contiguous 32B rows.
    if (tid < 512) {
        const int k = tid;
        const float* kr = Kp + (size_t)k * 8;
        float kv[8];
        float4 a = *(const float4*)(kr);
        float4 b = *(const float4*)(kr + 4);
        kv[0] = a.x; kv[1] = a.y; kv[2] = a.z; kv[3] = a.w;
        kv[4] = b.x; kv[5] = b.y; kv[6] = b.z; kv[7] = b.w;
        uint4 hi, lo;
        split_pack8(kv, &hi, &lo);
        ak1[k] = hi;
        ak2p[(k >> 5) * 33 + (k & 31)] = lo;
    }
    if (tid < 16) ak2p[tid * 33 + 32] = z4;

    // V-frag build: threads 0..639 (global gather; R5-proven path).
    if (tid < 640) {
        const int e = tid;
        if (e < 576) {
            int s  = e / 18;
            int r  = e % 18;
            int hv = r / 9;
            int n  = r % 9;
            float vv[8];
            #pragma unroll
            for (int j = 0; j < 8; ++j) {
                int key = 16 * s + ((j < 4) ? (4 * hv + j) : (8 + 4 * hv + (j - 4)));
                vv[j] = (n < 8) ? Vp[(size_t)key * 8 + n] : 1.0f;
            }
            uint4 hi, lo;
            split_pack8(vv, &hi, &lo);
            vfh[e] = hi;
            vfl[e] = lo;
        } else {
            vfh[e] = z4;
            vfl[e] = z4;
        }
    }

    __syncthreads();

    const float C = 0.51012091684045906f;  // log2(e)/sqrt(8)
    const int idx2 = hh ? 32 : l31;        // zero column for hh=1 lanes

    float16v Z16;
    #pragma unroll
    for (int i = 0; i < 16; ++i) Z16[i] = 0.f;

    {
        const float* qp = Qp + (size_t)(qt * 32 + l31) * 8;
        float qv[8];
        {
            float4 a = *(const float4*)(qp);
            float4 b = *(const float4*)(qp + 4);
            qv[0] = a.x * C; qv[1] = a.y * C; qv[2] = a.z * C; qv[3] = a.w * C;
            qv[4] = b.x * C; qv[5] = b.y * C; qv[6] = b.z * C; qv[7] = b.w * C;
        }
        uint4 qhi, qlo;
        split_pack8(qv, &qhi, &qlo);
        const uint4 bq1 = hh ? qlo : qhi;
        const uint4 bq2 = qhi;

        float16v O = Z16;

        for (int c = 0; c < 16; ++c) {
            const uint4 a1 = ak1[c * 32 + l31];
            const uint4 a2 = ak2p[c * 33 + idx2];

            float16v S;
            S = __builtin_amdgcn_mfma_f32_32x32x16_bf16(as_s8(a1), as_s8(bq1), Z16, 0, 0, 0);
            S = __builtin_amdgcn_mfma_f32_32x32x16_bf16(as_s8(a2), as_s8(bq2), S, 0, 0, 0);

            #pragma unroll
            for (int i = 0; i < 16; ++i) S[i] = fast_exp2(S[i]);

            uint4 ph0, pl0, ph1, pl1;
            split_pack8((const float*)&S, &ph0, &pl0);
            split_pack8(((const float*)&S) + 8, &ph1, &pl1);

            // Half 0 (shorter frag liveness), then half 1; single O chain.
            const int vi0 = (4 * c + hh) * 9;
            const uint4 bh0 = vfh[vi0 + l31];
            const uint4 bl0 = vfl[vi0 + l31];
            O = __builtin_amdgcn_mfma_f32_32x32x16_bf16(as_s8(ph0), as_s8(bh0), O, 0, 0, 0);
            O = __builtin_amdgcn_mfma_f32_32x32x16_bf16(as_s8(pl0), as_s8(bh0), O, 0, 0, 0);
            O = __builtin_amdgcn_mfma_f32_32x32x16_bf16(as_s8(ph0), as_s8(bl0), O, 0, 0, 0);

            const int vi1 = (4 * c + 2 + hh) * 9;
            const uint4 bh1 = vfh[vi1 + l31];
            const uint4 bl1 = vfl[vi1 + l31];
            O = __builtin_amdgcn_mfma_f32_32x32x16_bf16(as_s8(ph1), as_s8(bh1), O, 0, 0, 0);
            O = __builtin_amdgcn_mfma_f32_32x32x16_bf16(as_s8(pl1), as_s8(bh1), O, 0, 0, 0);
            O = __builtin_amdgcn_mfma_f32_32x32x16_bf16(as_s8(ph1), as_s8(bl1), O, 0, 0, 0);
        }

        #pragma unroll
        for (int r = 0; r < 16; ++r) {
            float ov = O[r];
            float den = __uint_as_float(
                __builtin_amdgcn_ds_swizzle(__float_as_uint(ov), 0x100));
            float o = ov * fast_rcp(den);
            if (l31 < 8) {
                int row = (r & 3) + 8 * (r >> 2) + 4 * hh;
                obuf[hb + (size_t)(qt * 32 + row) * 8 + l31] = o;
            }
        }
    }
}

// ---------------------------------------------------------------------------
// Kernel 3 (R13, kept): fused projection; Ts padded to 84.
// ---------------------------------------------------------------------------
__global__ __launch_bounds__(128) void proj_kernel(
    const float* __restrict__ obuf,
    const uint4* __restrict__ WfH, const uint4* __restrict__ WfL,
    const float* __restrict__ b10, const float* __restrict__ b11,
    float* __restrict__ out)
{
    __shared__ float Ts[32][84];

    const int tid  = threadIdx.x;
    const int lane = tid & 63;
    const int l31  = lane & 31;
    const int hh   = lane >> 5;
    const int tw   = tid >> 6;               // 0/1: column half this wave owns
    const size_t row = (size_t)blockIdx.x * 32 + l31;
    const size_t blockrow = (size_t)blockIdx.x * 32;

    float16v accM, accC;
    #pragma unroll
    for (int i = 0; i < 16; ++i) { accM[i] = 0.f; accC[i] = 0.f; }

    #pragma unroll
    for (int c = 0; c < 4; ++c) {
        // A-frag cols c*16+hh*8..+7 = head plane 2c+hh, contiguous row.
        const float* ap = obuf + (size_t)(2 * c + hh) * HPLANE + row * 8;
        float av[8];
        {
            float4 a0 = *(const float4*)(ap);
            float4 a1 = *(const float4*)(ap + 4);
            av[0] = a0.x; av[1] = a0.y; av[2] = a0.z; av[3] = a0.w;
            av[4] = a1.x; av[5] = a1.y; av[6] = a1.z; av[7] = a1.w;
        }
        uint4 ahi, alo;
        split_pack8(av, &ahi, &alo);

        const int ei = 3072 + c * 128 + hh * 64 + tw * 32 + l31;   // W10
        const uint4 bh = WfH[ei];
        const uint4 bl = WfL[ei];
        accM = __builtin_amdgcn_mfma_f32_32x32x16_bf16(
            as_s8(ahi), as_s8(bh), accM, 0, 0, 0);
        accC = __builtin_amdgcn_mfma_f32_32x32x16_bf16(
            as_s8(alo), as_s8(bh), accC, 0, 0, 0);
        accC = __builtin_amdgcn_mfma_f32_32x32x16_bf16(
            as_s8(ahi), as_s8(bl), accC, 0, 0, 0);
    }

    {
        const int col = tw * 32 + l31;
        const float bias = b10[col];
        #pragma unroll
        for (int r = 0; r < 16; ++r) {
            const int rowC = (r & 3) + 8 * (r >> 2) + 4 * hh;
            Ts[rowC][col] = fmaxf(accM[r] + accC[r] + bias, 0.f);
        }
    }
    __syncthreads();

    #pragma unroll
    for (int i = 0; i < 16; ++i) { accM[i] = 0.f; accC[i] = 0.f; }

    #pragma unroll
    for (int c = 0; c < 4; ++c) {
        const float* ap = &Ts[l31][c * 16 + hh * 8];
        float av[8];
        {
            float4 a0 = *(const float4*)(ap);
            float4 a1 = *(const float4*)(ap + 4);
            av[0] = a0.x; av[1] = a0.y; av[2] = a0.z; av[3] = a0.w;
            av[4] = a1.x; av[5] = a1.y; av[6] = a1.z; av[7] = a1.w;
        }
        uint4 ahi, alo;
        split_pack8(av, &ahi, &alo);

        const int ei = 3584 + c * 128 + hh * 64 + tw * 32 + l31;   // W11
        const uint4 bh = WfH[ei];
        const uint4 bl = WfL[ei];
        accM = __builtin_amdgcn_mfma_f32_32x32x16_bf16(
            as_s8(ahi), as_s8(bh), accM, 0, 0, 0);
        accC = __builtin_amdgcn_mfma_f32_32x32x16_bf16(
            as_s8(alo), as_s8(bh), accC, 0, 0, 0);
        accC = __builtin_amdgcn_mfma_f32_32x32x16_bf16(
            as_s8(ahi), as_s8(bl), accC, 0, 0, 0);
    }

    {
        const int col = tw * 32 + l31;
        const float bias = b11[col];
        #pragma unroll
        for (int r = 0; r < 16; ++r) {
            const int rowC = (r & 3) + 8 * (r >> 2) + 4 * hh;
            out[(blockrow + rowC) * 64 + col] = accM[r] + accC[r] + bias;
        }
    }
}

// ---------------------------------------------------------------------------
extern "C" void kernel_launch(void* const* d_in, const int* in_sizes, int n_in,
                              void* d_out, int out_size, void* d_ws, size_t ws_size,
                              hipStream_t stream)
{
    const float* X   = (const float*)d_in[0];
    const float* STE = (const float*)d_in[1];
    const float* W7  = (const float*)d_in[2];
    const float* b7  = (const float*)d_in[3];
    const float* W8  = (const float*)d_in[4];
    const float* b8  = (const float*)d_in[5];
    const float* W9  = (const float*)d_in[6];
    const float* b9  = (const float*)d_in[7];
    const float* W10 = (const float*)d_in[8];
    const float* b10 = (const float*)d_in[9];
    const float* W11 = (const float*)d_in[10];
    const float* b11 = (const float*)d_in[11];

    float* ws  = (float*)d_ws;   // Q | K | V | O | Wf
    float* out = (float*)d_out;

    uint4* WfH = (uint4*)(ws + WOFF);
    uint4* WfL = WfH + 4096;

    wprep_kernel<<<dim3(16), 256, 0, stream>>>(W7, W8, W9, W10, W11, WfH, WfL);
    qkv_kernel<<<dim3(RTOT / 32), 384, 0, stream>>>(X, STE, WfH, WfL, b7, b8, b9, ws);
    attn_kernel<<<dim3(BT * 8), 1024, 0, stream>>>(ws, ws + OOFF);
    proj_kernel<<<dim3(RTOT / 32), 128, 0, stream>>>(ws + OOFF, WfH, WfL, b10, b11, out);
}

// Round 9
// 172.036 us; speedup vs baseline: 1.0166x; 1.0087x over previous
//
#include <hip/hip_runtime.h>
#include <hip/hip_bf16.h>
#include <math.h>

// Problem constants
#define BT    96          // B*T = 8*12
#define NSEQ  512         // N
#define DMODEL 64         // D = K*d
#define RTOT  (BT * NSEQ) // 49152 rows

// Workspace layout (floats). Q/K/V and O are HEAD-MAJOR: [head][row][8],
// row = bt*512 + n. Offsets unchanged in size.
#define QOFF  0
#define KOFF  ((size_t)RTOT * DMODEL)
#define VOFF  ((size_t)2 * RTOT * DMODEL)
#define OOFF  ((size_t)3 * RTOT * DMODEL)
#define WOFF  ((size_t)4 * RTOT * DMODEL)   // W-fragment cache (128 KB)

#define HPLANE ((size_t)RTOT * 8)           // floats per head plane

// Guaranteed single-instruction 2^x / 1/x.
static __device__ inline float fast_exp2(float x) {
#if __has_builtin(__builtin_amdgcn_exp2f)
    return __builtin_amdgcn_exp2f(x);
#else
    float r; asm("v_exp_f32 %0, %1" : "=v"(r) : "v"(x)); return r;
#endif
}
static __device__ inline float fast_rcp(float x) {
#if __has_builtin(__builtin_amdgcn_rcpf)
    return __builtin_amdgcn_rcpf(x);
#else
    return 1.f / x;
#endif
}

typedef __attribute__((ext_vector_type(8)))  short short8;
typedef __attribute__((ext_vector_type(16))) float float16v;

static __device__ inline short8 as_s8(uint4 u) {
    union { uint4 u; short8 s; } x; x.u = u; return x.s;
}

static __device__ inline uint32_t bf162_bits(__hip_bfloat162 h) {
    union { __hip_bfloat162 h; uint32_t u; } x; x.h = h; return x.u;
}

// Split 8 fp32 into packed bf16 hi (RNE) + bf16 lo (exact residual, RNE).
static __device__ inline void split_pack8(const float* v, uint4* hi, uint4* lo) {
    uint32_t h[4], l[4];
    #pragma unroll
    for (int t = 0; t < 4; ++t) {
        float x0 = v[2 * t], x1 = v[2 * t + 1];
        uint32_t hw = bf162_bits(__float22bfloat162_rn(make_float2(x0, x1)));
        float h0 = __uint_as_float(hw << 16);
        float h1 = __uint_as_float(hw & 0xffff0000u);
        h[t] = hw;
        float l0 = x0 - h0;
        float l1 = x1 - h1;
        l[t] = bf162_bits(__float22bfloat162_rn(make_float2(l0, l1)));
    }
    *hi = make_uint4(h[0], h[1], h[2], h[3]);
    *lo = make_uint4(l[0], l[1], l[2], l[3]);
}

// ---------------------------------------------------------------------------
// Kernel 0: pre-split W7/8/9 (K=128) and W10/W11 (K=64) into bf16 hi/lo
// B-fragment layout. [0,3072) = W789; [3072,3584) = W10; [3584,4096) = W11.
// ---------------------------------------------------------------------------
__global__ __launch_bounds__(256) void wprep_kernel(
    const float* __restrict__ W7, const float* __restrict__ W8,
    const float* __restrict__ W9, const float* __restrict__ W10,
    const float* __restrict__ W11,
    uint4* __restrict__ WfH, uint4* __restrict__ WfL)
{
    const int e = blockIdx.x * 256 + threadIdx.x;   // 0..4095
    const float* W;
    int k0, col;
    if (e < 3072) {
        int n  = e & 31;
        int t  = (e >> 5) & 1;
        int hh = (e >> 6) & 1;
        int c  = (e >> 7) & 7;
        int w  = e >> 10;
        W = (w == 0) ? W7 : (w == 1) ? W8 : W9;
        k0 = c * 16 + hh * 8;
        col = t * 32 + n;
    } else {
        int pe = e - 3072;
        int n  = pe & 31;
        int t  = (pe >> 5) & 1;
        int hh = (pe >> 6) & 1;
        int c  = (pe >> 7) & 3;
        int m  = pe >> 9;
        W = (m == 0) ? W10 : W11;
        k0 = c * 16 + hh * 8;
        col = t * 32 + n;
    }
    float v[8];
    #pragma unroll
    for (int j = 0; j < 8; ++j) v[j] = W[(size_t)(k0 + j) * 64 + col];
    uint4 hi, lo;
    split_pack8(v, &hi, &lo);
    WfH[e] = hi;
    WfL[e] = lo;
}

// ---------------------------------------------------------------------------
// Kernel 1 (R14, kept): fused-W QKV, 6 waves/block, coalesced staging,
// direct head-major stores.
// ---------------------------------------------------------------------------
__global__ __launch_bounds__(384) void qkv_kernel(
    const float* __restrict__ X, const float* __restrict__ STE,
    const uint4* __restrict__ WfH, const uint4* __restrict__ WfL,
    const float* __restrict__ b7, const float* __restrict__ b8,
    const float* __restrict__ b9,
    float* __restrict__ qkv)
{
    __shared__ float Xs[32][132];  // 16.9 KB raw [X|STE] rows (pad vs conflicts)
    __shared__ uint4 aH[512];      // 8 KB: A_hi frags, entry = c*64 + hh*32 + l31
    __shared__ uint4 aL[512];      // 8 KB: A_lo frags

    const int tid  = threadIdx.x;
    const int l31  = tid & 31;
    const int hh   = (tid >> 5) & 1;
    const int wave = tid >> 6;              // 0..5
    const int w    = wave >> 1;             // 0,1,2 -> W7,W8,W9
    const int tt   = wave & 1;              // column half
    const size_t blockrow = (size_t)blockIdx.x * 32;

    // Phase 1: coalesced raw stage. 1024 float4s: row = e>>5, seg = e&31.
    for (int e = tid; e < 1024; e += 384) {
        const int row = e >> 5;
        const int seg = e & 31;
        const float* src = (seg < 16) ? X : STE;
        const float4 v = *(const float4*)(src + (blockrow + row) * 64 + (seg & 15) * 4);
        float* dst = &Xs[row][seg * 4];
        dst[0] = v.x; dst[1] = v.y; dst[2] = v.z; dst[3] = v.w;
    }
    __syncthreads();

    // Phase 2: build split frags from LDS (split once, consumed by 6 waves).
    for (int e = tid; e < 512; e += 384) {
        const int el  = e & 31;
        const int ehh = (e >> 5) & 1;
        const int ec  = e >> 6;
        const float* hp = &Xs[el][ec * 16 + ehh * 8];
        float av[8];
        #pragma unroll
        for (int j = 0; j < 8; ++j) av[j] = hp[j];
        uint4 hi, lo;
        split_pack8(av, &hi, &lo);
        aH[e] = hi;
        aL[e] = lo;
    }
    __syncthreads();

    float16v accM, accC;
    #pragma unroll
    for (int i = 0; i < 16; ++i) { accM[i] = 0.f; accC[i] = 0.f; }

    #pragma unroll
    for (int c = 0; c < 8; ++c) {
        const uint4 ahi = aH[c * 64 + hh * 32 + l31];
        const uint4 alo = aL[c * 64 + hh * 32 + l31];
        const int ei = w * 1024 + c * 128 + hh * 64 + tt * 32 + l31;
        const uint4 bh = WfH[ei];
        const uint4 bl = WfL[ei];
        accM = __builtin_amdgcn_mfma_f32_32x32x16_bf16(
            as_s8(ahi), as_s8(bh), accM, 0, 0, 0);
        accC = __builtin_amdgcn_mfma_f32_32x32x16_bf16(
            as_s8(alo), as_s8(bh), accC, 0, 0, 0);
        accC = __builtin_amdgcn_mfma_f32_32x32x16_bf16(
            as_s8(ahi), as_s8(bl), accC, 0, 0, 0);
    }

    const float* bv = (w == 0) ? b7 : (w == 1) ? b8 : b9;
    // Head-major store: col = tt*32+l31 = head*8 + d.
    const int head = tt * 4 + (l31 >> 3);
    const int d    = l31 & 7;
    const int col  = tt * 32 + l31;
    float* obase = qkv + (size_t)w * ((size_t)RTOT * DMODEL) + (size_t)head * HPLANE;
    const float bias = bv[col];
    #pragma unroll
    for (int r = 0; r < 16; ++r) {
        const int rowC = (r & 3) + 8 * (r >> 2) + 4 * hh;
        obase[(blockrow + rowC) * 8 + d] =
            fmaxf(accM[r] + accC[r] + bias, 0.f);
    }
}

// ---------------------------------------------------------------------------
// Kernel 2 (R16): attention, 768 blocks x 1024 threads (R15 shape) +
// S-prefetch software pipeline: iteration c's exp/pack (VALU+trans pipes)
// overlaps iteration c+1's S-MFMAs. Explicit Sa/Sb double buffer (two-body
// loop, no per-iter S register copy). NOTE: R3's version of this failed on
// VGPR->occupancy loss; at 1024-thr blocks the CU is wave-slot-capped
// (2 blocks = 32 waves max) so extra VGPRs are now free (8w x ~90 <= 2048).
// ---------------------------------------------------------------------------
__global__ __launch_bounds__(1024) void attn_kernel(
    const float* __restrict__ qkv, float* __restrict__ obuf)
{
    __shared__ uint4 ak1[16 * 32];    //  8.0 KB  k_hi
    __shared__ uint4 ak2p[16 * 33];   //  8.3 KB  k_lo | zero column
    __shared__ uint4 vfh[640];        // 10.0 KB  V_hi frags (+zero pad)
    __shared__ uint4 vfl[640];        // 10.0 KB  V_lo frags (+zero pad)

    const int tid  = threadIdx.x;
    const int lane = tid & 63;
    const int l31  = lane & 31;
    const int hh   = lane >> 5;
    const int qt   = tid >> 6;               // 0..15: this wave's q-tile
    const int head = blockIdx.x & 7;
    const int bt   = blockIdx.x >> 3;

    // Head-major base: plane 'head', rows bt*512..bt*512+511, 8 floats/row.
    const size_t hb = (size_t)head * HPLANE + (size_t)bt * (NSEQ * 8);
    const float* Qp = qkv + QOFF + hb;
    const float* Kp = qkv + KOFF + hb;
    const float* Vp = qkv + VOFF + hb;

    const uint4 z4 = make_uint4(0, 0, 0, 0);

    // K staging: threads 0..511, contiguous 32B rows.
    if (tid < 512) {
        const int k = tid;
        const float* kr = Kp + (size_t)k * 8;
        float kv[8];
        float4 a = *(const float4*)(kr);
        float4 b = *(const float4*)(kr + 4);
        kv[0] = a.x; kv[1] = a.y; kv[2] = a.z; kv[3] = a.w;
        kv[4] = b.x; kv[5] = b.y; kv[6] = b.z; kv[7] = b.w;
        uint4 hi, lo;
        split_pack8(kv, &hi, &lo);
        ak1[k] = hi;
        ak2p[(k >> 5) * 33 + (k & 31)] = lo;
    }
    if (tid < 16) ak2p[tid * 33 + 32] = z4;

    // V-frag build: threads 0..639 (global gather; R5-proven path).
    if (tid < 640) {
        const int e = tid;
        if (e < 576) {
            int s  = e / 18;
            int r  = e % 18;
            int hv = r / 9;
            int n  = r % 9;
            float vv[8];
            #pragma unroll
            for (int j = 0; j < 8; ++j) {
                int key = 16 * s + ((j < 4) ? (4 * hv + j) : (8 + 4 * hv + (j - 4)));
                vv[j] = (n < 8) ? Vp[(size_t)key * 8 + n] : 1.0f;
            }
            uint4 hi, lo;
            split_pack8(vv, &hi, &lo);
            vfh[e] = hi;
            vfl[e] = lo;
        } else {
            vfh[e] = z4;
            vfl[e] = z4;
        }
    }

    __syncthreads();

    const float C = 0.51012091684045906f;  // log2(e)/sqrt(8)
    const int idx2 = hh ? 32 : l31;        // zero column for hh=1 lanes

    float16v Z16;
    #pragma unroll
    for (int i = 0; i < 16; ++i) Z16[i] = 0.f;

    {
        const float* qp = Qp + (size_t)(qt * 32 + l31) * 8;
        float qv[8];
        {
            float4 a = *(const float4*)(qp);
            float4 b = *(const float4*)(qp + 4);
            qv[0] = a.x * C; qv[1] = a.y * C; qv[2] = a.z * C; qv[3] = a.w * C;
            qv[4] = b.x * C; qv[5] = b.y * C; qv[6] = b.z * C; qv[7] = b.w * C;
        }
        uint4 qhi, qlo;
        split_pack8(qv, &qhi, &qlo);
        const uint4 bq1 = hh ? qlo : qhi;
        const uint4 bq2 = qhi;

        float16v O = Z16;

        // Prologue: S for c=0.
        float16v Sa, Sb;
        {
            const uint4 a1 = ak1[l31];
            const uint4 a2 = ak2p[idx2];
            Sa = __builtin_amdgcn_mfma_f32_32x32x16_bf16(as_s8(a1), as_s8(bq1), Z16, 0, 0, 0);
            Sa = __builtin_amdgcn_mfma_f32_32x32x16_bf16(as_s8(a2), as_s8(bq2), Sa, 0, 0, 0);
        }

        // One pipelined step: consume Scur (exp/pack/O-MFMA) while issuing
        // the S-MFMAs for iteration cn into Snext. FP order per accumulator
        // chain identical to R15 -> bitwise-identical output.
#define ATTN_STEP(Scur, Snext, cc, cn)                                         \
        {                                                                      \
            const int vi0 = (4 * (cc) + hh) * 9;                               \
            const int vi1 = (4 * (cc) + 2 + hh) * 9;                           \
            const uint4 bh0 = vfh[vi0 + l31];                                  \
            const uint4 bl0 = vfl[vi0 + l31];                                  \
            const uint4 bh1 = vfh[vi1 + l31];                                  \
            const uint4 bl1 = vfl[vi1 + l31];                                  \
            const uint4 a1n = ak1[(cn) * 32 + l31];                            \
            const uint4 a2n = ak2p[(cn) * 33 + idx2];                          \
            Snext = __builtin_amdgcn_mfma_f32_32x32x16_bf16(                   \
                as_s8(a1n), as_s8(bq1), Z16, 0, 0, 0);                         \
            Snext = __builtin_amdgcn_mfma_f32_32x32x16_bf16(                   \
                as_s8(a2n), as_s8(bq2), Snext, 0, 0, 0);                       \
            _Pragma("unroll")                                                  \
            for (int i = 0; i < 16; ++i) Scur[i] = fast_exp2(Scur[i]);         \
            uint4 ph0, pl0, ph1, pl1;                                          \
            split_pack8((const float*)&Scur, &ph0, &pl0);                      \
            split_pack8(((const float*)&Scur) + 8, &ph1, &pl1);                \
            O = __builtin_amdgcn_mfma_f32_32x32x16_bf16(                       \
                as_s8(ph0), as_s8(bh0), O, 0, 0, 0);                           \
            O = __builtin_amdgcn_mfma_f32_32x32x16_bf16(                       \
                as_s8(pl0), as_s8(bh0), O, 0, 0, 0);                           \
            O = __builtin_amdgcn_mfma_f32_32x32x16_bf16(                       \
                as_s8(ph0), as_s8(bl0), O, 0, 0, 0);                           \
            O = __builtin_amdgcn_mfma_f32_32x32x16_bf16(                       \
                as_s8(ph1), as_s8(bh1), O, 0, 0, 0);                           \
            O = __builtin_amdgcn_mfma_f32_32x32x16_bf16(                       \
                as_s8(pl1), as_s8(bh1), O, 0, 0, 0);                           \
            O = __builtin_amdgcn_mfma_f32_32x32x16_bf16(                       \
                as_s8(ph1), as_s8(bl1), O, 0, 0, 0);                           \
        }

        for (int c = 0; c < 16; c += 2) {
            ATTN_STEP(Sa, Sb, c, c + 1);
            ATTN_STEP(Sb, Sa, c + 1, (c + 2) & 15);  // last prefetch discarded
        }
#undef ATTN_STEP

        #pragma unroll
        for (int r = 0; r < 16; ++r) {
            float ov = O[r];
            float den = __uint_as_float(
                __builtin_amdgcn_ds_swizzle(__float_as_uint(ov), 0x100));
            float o = ov * fast_rcp(den);
            if (l31 < 8) {
                int row = (r & 3) + 8 * (r >> 2) + 4 * hh;
                obuf[hb + (size_t)(qt * 32 + row) * 8 + l31] = o;
            }
        }
    }
}

// ---------------------------------------------------------------------------
// Kernel 3 (R13, kept): fused projection; Ts padded to 84.
// ---------------------------------------------------------------------------
__global__ __launch_bounds__(128) void proj_kernel(
    const float* __restrict__ obuf,
    const uint4* __restrict__ WfH, const uint4* __restrict__ WfL,
    const float* __restrict__ b10, const float* __restrict__ b11,
    float* __restrict__ out)
{
    __shared__ float Ts[32][84];

    const int tid  = threadIdx.x;
    const int lane = tid & 63;
    const int l31  = lane & 31;
    const int hh   = lane >> 5;
    const int tw   = tid >> 6;               // 0/1: column half this wave owns
    const size_t row = (size_t)blockIdx.x * 32 + l31;
    const size_t blockrow = (size_t)blockIdx.x * 32;

    float16v accM, accC;
    #pragma unroll
    for (int i = 0; i < 16; ++i) { accM[i] = 0.f; accC[i] = 0.f; }

    #pragma unroll
    for (int c = 0; c < 4; ++c) {
        // A-frag cols c*16+hh*8..+7 = head plane 2c+hh, contiguous row.
        const float* ap = obuf + (size_t)(2 * c + hh) * HPLANE + row * 8;
        float av[8];
        {
            float4 a0 = *(const float4*)(ap);
            float4 a1 = *(const float4*)(ap + 4);
            av[0] = a0.x; av[1] = a0.y; av[2] = a0.z; av[3] = a0.w;
            av[4] = a1.x; av[5] = a1.y; av[6] = a1.z; av[7] = a1.w;
        }
        uint4 ahi, alo;
        split_pack8(av, &ahi, &alo);

        const int ei = 3072 + c * 128 + hh * 64 + tw * 32 + l31;   // W10
        const uint4 bh = WfH[ei];
        const uint4 bl = WfL[ei];
        accM = __builtin_amdgcn_mfma_f32_32x32x16_bf16(
            as_s8(ahi), as_s8(bh), accM, 0, 0, 0);
        accC = __builtin_amdgcn_mfma_f32_32x32x16_bf16(
            as_s8(alo), as_s8(bh), accC, 0, 0, 0);
        accC = __builtin_amdgcn_mfma_f32_32x32x16_bf16(
            as_s8(ahi), as_s8(bl), accC, 0, 0, 0);
    }

    {
        const int col = tw * 32 + l31;
        const float bias = b10[col];
        #pragma unroll
        for (int r = 0; r < 16; ++r) {
            const int rowC = (r & 3) + 8 * (r >> 2) + 4 * hh;
            Ts[rowC][col] = fmaxf(accM[r] + accC[r] + bias, 0.f);
        }
    }
    __syncthreads();

    #pragma unroll
    for (int i = 0; i < 16; ++i) { accM[i] = 0.f; accC[i] = 0.f; }

    #pragma unroll
    for (int c = 0; c < 4; ++c) {
        const float* ap = &Ts[l31][c * 16 + hh * 8];
        float av[8];
        {
            float4 a0 = *(const float4*)(ap);
            float4 a1 = *(const float4*)(ap + 4);
            av[0] = a0.x; av[1] = a0.y; av[2] = a0.z; av[3] = a0.w;
            av[4] = a1.x; av[5] = a1.y; av[6] = a1.z; av[7] = a1.w;
        }
        uint4 ahi, alo;
        split_pack8(av, &ahi, &alo);

        const int ei = 3584 + c * 128 + hh * 64 + tw * 32 + l31;   // W11
        const uint4 bh = WfH[ei];
        const uint4 bl = WfL[ei];
        accM = __builtin_amdgcn_mfma_f32_32x32x16_bf16(
            as_s8(ahi), as_s8(bh), accM, 0, 0, 0);
        accC = __builtin_amdgcn_mfma_f32_32x32x16_bf16(
            as_s8(alo), as_s8(bh), accC, 0, 0, 0);
        accC = __builtin_amdgcn_mfma_f32_32x32x16_bf16(
            as_s8(ahi), as_s8(bl), accC, 0, 0, 0);
    }

    {
        const int col = tw * 32 + l31;
        const float bias = b11[col];
        #pragma unroll
        for (int r = 0; r < 16; ++r) {
            const int rowC = (r & 3) + 8 * (r >> 2) + 4 * hh;
            out[(blockrow + rowC) * 64 + col] = accM[r] + accC[r] + bias;
        }
    }
}

// ---------------------------------------------------------------------------
extern "C" void kernel_launch(void* const* d_in, const int* in_sizes, int n_in,
                              void* d_out, int out_size, void* d_ws, size_t ws_size,
                              hipStream_t stream)
{
    const float* X   = (const float*)d_in[0];
    const float* STE = (const float*)d_in[1];
    const float* W7  = (const float*)d_in[2];
    const float* b7  = (const float*)d_in[3];
    const float* W8  = (const float*)d_in[4];
    const float* b8  = (const float*)d_in[5];
    const float* W9  = (const float*)d_in[6];
    const float* b9  = (const float*)d_in[7];
    const float* W10 = (const float*)d_in[8];
    const float* b10 = (const float*)d_in[9];
    const float* W11 = (const float*)d_in[10];
    const float* b11 = (const float*)d_in[11];

    float* ws  = (float*)d_ws;   // Q | K | V | O | Wf
    float* out = (float*)d_out;

    uint4* WfH = (uint4*)(ws + WOFF);
    uint4* WfL = WfH + 4096;

    wprep_kernel<<<dim3(16), 256, 0, stream>>>(W7, W8, W9, W10, W11, WfH, WfL);
    qkv_kernel<<<dim3(RTOT / 32), 384, 0, stream>>>(X, STE, WfH, WfL, b7, b8, b9, ws);
    attn_kernel<<<dim3(BT * 8), 1024, 0, stream>>>(ws, ws + OOFF);
    proj_kernel<<<dim3(RTOT / 32), 128, 0, stream>>>(ws + OOFF, WfH, WfL, b10, b11, out);
}

// Round 10
// 156.634 us; speedup vs baseline: 1.1166x; 1.0983x over previous
//
#include <hip/hip_runtime.h>
#include <hip/hip_bf16.h>
#include <math.h>

// Problem constants
#define BT    96          // B*T = 8*12
#define NSEQ  512         // N
#define DMODEL 64         // D = K*d
#define RTOT  (BT * NSEQ) // 49152 rows

// Workspace layout (floats). Q/K/V and O are HEAD-MAJOR: [head][row][8],
// row = bt*512 + n. Offsets unchanged in size.
#define QOFF  0
#define KOFF  ((size_t)RTOT * DMODEL)
#define VOFF  ((size_t)2 * RTOT * DMODEL)
#define OOFF  ((size_t)3 * RTOT * DMODEL)
#define WOFF  ((size_t)4 * RTOT * DMODEL)   // W-fragment cache (128 KB)

#define HPLANE ((size_t)RTOT * 8)           // floats per head plane

// Guaranteed single-instruction 2^x / 1/x.
static __device__ inline float fast_exp2(float x) {
#if __has_builtin(__builtin_amdgcn_exp2f)
    return __builtin_amdgcn_exp2f(x);
#else
    float r; asm("v_exp_f32 %0, %1" : "=v"(r) : "v"(x)); return r;
#endif
}
static __device__ inline float fast_rcp(float x) {
#if __has_builtin(__builtin_amdgcn_rcpf)
    return __builtin_amdgcn_rcpf(x);
#else
    return 1.f / x;
#endif
}

typedef __attribute__((ext_vector_type(8)))  short short8;
typedef __attribute__((ext_vector_type(16))) float float16v;

static __device__ inline short8 as_s8(uint4 u) {
    union { uint4 u; short8 s; } x; x.u = u; return x.s;
}

static __device__ inline uint32_t bf162_bits(__hip_bfloat162 h) {
    union { __hip_bfloat162 h; uint32_t u; } x; x.h = h; return x.u;
}

// Split 8 fp32 into packed bf16 hi (RNE) + bf16 lo (exact residual, RNE).
static __device__ inline void split_pack8(const float* v, uint4* hi, uint4* lo) {
    uint32_t h[4], l[4];
    #pragma unroll
    for (int t = 0; t < 4; ++t) {
        float x0 = v[2 * t], x1 = v[2 * t + 1];
        uint32_t hw = bf162_bits(__float22bfloat162_rn(make_float2(x0, x1)));
        float h0 = __uint_as_float(hw << 16);
        float h1 = __uint_as_float(hw & 0xffff0000u);
        h[t] = hw;
        float l0 = x0 - h0;
        float l1 = x1 - h1;
        l[t] = bf162_bits(__float22bfloat162_rn(make_float2(l0, l1)));
    }
    *hi = make_uint4(h[0], h[1], h[2], h[3]);
    *lo = make_uint4(l[0], l[1], l[2], l[3]);
}

// Hi-only pack: 8 fp32 -> packed bf16 (RNE). 4 VALU ops (vs 24 for split).
static __device__ inline uint4 pack_hi8(const float* v) {
    uint32_t h[4];
    #pragma unroll
    for (int t = 0; t < 4; ++t)
        h[t] = bf162_bits(__float22bfloat162_rn(make_float2(v[2 * t], v[2 * t + 1])));
    return make_uint4(h[0], h[1], h[2], h[3]);
}

// ---------------------------------------------------------------------------
// Kernel 0: pre-split W7/8/9 (K=128) and W10/W11 (K=64) into bf16 hi/lo
// B-fragment layout. [0,3072) = W789; [3072,3584) = W10; [3584,4096) = W11.
// ---------------------------------------------------------------------------
__global__ __launch_bounds__(256) void wprep_kernel(
    const float* __restrict__ W7, const float* __restrict__ W8,
    const float* __restrict__ W9, const float* __restrict__ W10,
    const float* __restrict__ W11,
    uint4* __restrict__ WfH, uint4* __restrict__ WfL)
{
    const int e = blockIdx.x * 256 + threadIdx.x;   // 0..4095
    const float* W;
    int k0, col;
    if (e < 3072) {
        int n  = e & 31;
        int t  = (e >> 5) & 1;
        int hh = (e >> 6) & 1;
        int c  = (e >> 7) & 7;
        int w  = e >> 10;
        W = (w == 0) ? W7 : (w == 1) ? W8 : W9;
        k0 = c * 16 + hh * 8;
        col = t * 32 + n;
    } else {
        int pe = e - 3072;
        int n  = pe & 31;
        int t  = (pe >> 5) & 1;
        int hh = (pe >> 6) & 1;
        int c  = (pe >> 7) & 3;
        int m  = pe >> 9;
        W = (m == 0) ? W10 : W11;
        k0 = c * 16 + hh * 8;
        col = t * 32 + n;
    }
    float v[8];
    #pragma unroll
    for (int j = 0; j < 8; ++j) v[j] = W[(size_t)(k0 + j) * 64 + col];
    uint4 hi, lo;
    split_pack8(v, &hi, &lo);
    WfH[e] = hi;
    WfL[e] = lo;
}

// ---------------------------------------------------------------------------
// Kernel 1 (R14, kept): fused-W QKV, 6 waves/block, coalesced staging,
// direct head-major stores.
// ---------------------------------------------------------------------------
__global__ __launch_bounds__(384) void qkv_kernel(
    const float* __restrict__ X, const float* __restrict__ STE,
    const uint4* __restrict__ WfH, const uint4* __restrict__ WfL,
    const float* __restrict__ b7, const float* __restrict__ b8,
    const float* __restrict__ b9,
    float* __restrict__ qkv)
{
    __shared__ float Xs[32][132];  // 16.9 KB raw [X|STE] rows (pad vs conflicts)
    __shared__ uint4 aH[512];      // 8 KB: A_hi frags, entry = c*64 + hh*32 + l31
    __shared__ uint4 aL[512];      // 8 KB: A_lo frags

    const int tid  = threadIdx.x;
    const int l31  = tid & 31;
    const int hh   = (tid >> 5) & 1;
    const int wave = tid >> 6;              // 0..5
    const int w    = wave >> 1;             // 0,1,2 -> W7,W8,W9
    const int tt   = wave & 1;              // column half
    const size_t blockrow = (size_t)blockIdx.x * 32;

    // Phase 1: coalesced raw stage. 1024 float4s: row = e>>5, seg = e&31.
    for (int e = tid; e < 1024; e += 384) {
        const int row = e >> 5;
        const int seg = e & 31;
        const float* src = (seg < 16) ? X : STE;
        const float4 v = *(const float4*)(src + (blockrow + row) * 64 + (seg & 15) * 4);
        float* dst = &Xs[row][seg * 4];
        dst[0] = v.x; dst[1] = v.y; dst[2] = v.z; dst[3] = v.w;
    }
    __syncthreads();

    // Phase 2: build split frags from LDS (split once, consumed by 6 waves).
    for (int e = tid; e < 512; e += 384) {
        const int el  = e & 31;
        const int ehh = (e >> 5) & 1;
        const int ec  = e >> 6;
        const float* hp = &Xs[el][ec * 16 + ehh * 8];
        float av[8];
        #pragma unroll
        for (int j = 0; j < 8; ++j) av[j] = hp[j];
        uint4 hi, lo;
        split_pack8(av, &hi, &lo);
        aH[e] = hi;
        aL[e] = lo;
    }
    __syncthreads();

    float16v accM, accC;
    #pragma unroll
    for (int i = 0; i < 16; ++i) { accM[i] = 0.f; accC[i] = 0.f; }

    #pragma unroll
    for (int c = 0; c < 8; ++c) {
        const uint4 ahi = aH[c * 64 + hh * 32 + l31];
        const uint4 alo = aL[c * 64 + hh * 32 + l31];
        const int ei = w * 1024 + c * 128 + hh * 64 + tt * 32 + l31;
        const uint4 bh = WfH[ei];
        const uint4 bl = WfL[ei];
        accM = __builtin_amdgcn_mfma_f32_32x32x16_bf16(
            as_s8(ahi), as_s8(bh), accM, 0, 0, 0);
        accC = __builtin_amdgcn_mfma_f32_32x32x16_bf16(
            as_s8(alo), as_s8(bh), accC, 0, 0, 0);
        accC = __builtin_amdgcn_mfma_f32_32x32x16_bf16(
            as_s8(ahi), as_s8(bl), accC, 0, 0, 0);
    }

    const float* bv = (w == 0) ? b7 : (w == 1) ? b8 : b9;
    // Head-major store: col = tt*32+l31 = head*8 + d.
    const int head = tt * 4 + (l31 >> 3);
    const int d    = l31 & 7;
    const int col  = tt * 32 + l31;
    float* obase = qkv + (size_t)w * ((size_t)RTOT * DMODEL) + (size_t)head * HPLANE;
    const float bias = bv[col];
    #pragma unroll
    for (int r = 0; r < 16; ++r) {
        const int rowC = (r & 3) + 8 * (r >> 2) + 4 * hh;
        obase[(blockrow + rowC) * 8 + d] =
            fmaxf(accM[r] + accC[r] + bias, 0.f);
    }
}

// ---------------------------------------------------------------------------
// Kernel 2 (R17): attention. R16 structure, but P used HI-ONLY (coherent
// softmax with bf16 weights: num = sum P_hi*V, den = sum P_hi -> the bf16
// rounding of P partially cancels as a weighted-avg perturbation). Removes
// per c-iter: 40 VALU pack ops + 2 MFMAs (the pl*bh pair). VALU issue was
// the saturated pipe (VALUBusy 64.5 vs MfmaUtil 33.7 = the 128:64 static
// ratio); this cuts VALU-issue ~2.6x.
// ---------------------------------------------------------------------------
__global__ __launch_bounds__(1024) void attn_kernel(
    const float* __restrict__ qkv, float* __restrict__ obuf)
{
    __shared__ uint4 ak1[16 * 32];    //  8.0 KB  k_hi
    __shared__ uint4 ak2p[16 * 33];   //  8.3 KB  k_lo | zero column
    __shared__ uint4 vfh[640];        // 10.0 KB  V_hi frags (+zero pad)
    __shared__ uint4 vfl[640];        // 10.0 KB  V_lo frags (+zero pad)

    const int tid  = threadIdx.x;
    const int lane = tid & 63;
    const int l31  = lane & 31;
    const int hh   = lane >> 5;
    const int qt   = tid >> 6;               // 0..15: this wave's q-tile
    const int head = blockIdx.x & 7;
    const int bt   = blockIdx.x >> 3;

    // Head-major base: plane 'head', rows bt*512..bt*512+511, 8 floats/row.
    const size_t hb = (size_t)head * HPLANE + (size_t)bt * (NSEQ * 8);
    const float* Qp = qkv + QOFF + hb;
    const float* Kp = qkv + KOFF + hb;
    const float* Vp = qkv + VOFF + hb;

    const uint4 z4 = make_uint4(0, 0, 0, 0);

    // K staging: threads 0..511, contiguous 32B rows.
    if (tid < 512) {
        const int k = tid;
        const float* kr = Kp + (size_t)k * 8;
        float kv[8];
        float4 a = *(const float4*)(kr);
        float4 b = *(const float4*)(kr + 4);
        kv[0] = a.x; kv[1] = a.y; kv[2] = a.z; kv[3] = a.w;
        kv[4] = b.x; kv[5] = b.y; kv[6] = b.z; kv[7] = b.w;
        uint4 hi, lo;
        split_pack8(kv, &hi, &lo);
        ak1[k] = hi;
        ak2p[(k >> 5) * 33 + (k & 31)] = lo;
    }
    if (tid < 16) ak2p[tid * 33 + 32] = z4;

    // V-frag build: threads 0..639 (global gather; R5-proven path).
    if (tid < 640) {
        const int e = tid;
        if (e < 576) {
            int s  = e / 18;
            int r  = e % 18;
            int hv = r / 9;
            int n  = r % 9;
            float vv[8];
            #pragma unroll
            for (int j = 0; j < 8; ++j) {
                int key = 16 * s + ((j < 4) ? (4 * hv + j) : (8 + 4 * hv + (j - 4)));
                vv[j] = (n < 8) ? Vp[(size_t)key * 8 + n] : 1.0f;
            }
            uint4 hi, lo;
            split_pack8(vv, &hi, &lo);
            vfh[e] = hi;
            vfl[e] = lo;
        } else {
            vfh[e] = z4;
            vfl[e] = z4;
        }
    }

    __syncthreads();

    const float C = 0.51012091684045906f;  // log2(e)/sqrt(8)
    const int idx2 = hh ? 32 : l31;        // zero column for hh=1 lanes

    float16v Z16;
    #pragma unroll
    for (int i = 0; i < 16; ++i) Z16[i] = 0.f;

    {
        const float* qp = Qp + (size_t)(qt * 32 + l31) * 8;
        float qv[8];
        {
            float4 a = *(const float4*)(qp);
            float4 b = *(const float4*)(qp + 4);
            qv[0] = a.x * C; qv[1] = a.y * C; qv[2] = a.z * C; qv[3] = a.w * C;
            qv[4] = b.x * C; qv[5] = b.y * C; qv[6] = b.z * C; qv[7] = b.w * C;
        }
        uint4 qhi, qlo;
        split_pack8(qv, &qhi, &qlo);
        const uint4 bq1 = hh ? qlo : qhi;
        const uint4 bq2 = qhi;

        float16v O = Z16;

        // Prologue: S for c=0.
        float16v Sa, Sb;
        {
            const uint4 a1 = ak1[l31];
            const uint4 a2 = ak2p[idx2];
            Sa = __builtin_amdgcn_mfma_f32_32x32x16_bf16(as_s8(a1), as_s8(bq1), Z16, 0, 0, 0);
            Sa = __builtin_amdgcn_mfma_f32_32x32x16_bf16(as_s8(a2), as_s8(bq2), Sa, 0, 0, 0);
        }

        // One pipelined step: consume Scur (exp/pack-hi/O-MFMA) while issuing
        // the S-MFMAs for iteration cn into Snext.
#define ATTN_STEP(Scur, Snext, cc, cn)                                         \
        {                                                                      \
            const int vi0 = (4 * (cc) + hh) * 9;                               \
            const int vi1 = (4 * (cc) + 2 + hh) * 9;                           \
            const uint4 bh0 = vfh[vi0 + l31];                                  \
            const uint4 bl0 = vfl[vi0 + l31];                                  \
            const uint4 bh1 = vfh[vi1 + l31];                                  \
            const uint4 bl1 = vfl[vi1 + l31];                                  \
            const uint4 a1n = ak1[(cn) * 32 + l31];                            \
            const uint4 a2n = ak2p[(cn) * 33 + idx2];                          \
            Snext = __builtin_amdgcn_mfma_f32_32x32x16_bf16(                   \
                as_s8(a1n), as_s8(bq1), Z16, 0, 0, 0);                         \
            Snext = __builtin_amdgcn_mfma_f32_32x32x16_bf16(                   \
                as_s8(a2n), as_s8(bq2), Snext, 0, 0, 0);                       \
            _Pragma("unroll")                                                  \
            for (int i = 0; i < 16; ++i) Scur[i] = fast_exp2(Scur[i]);         \
            const uint4 ph0 = pack_hi8((const float*)&Scur);                   \
            const uint4 ph1 = pack_hi8(((const float*)&Scur) + 8);             \
            O = __builtin_amdgcn_mfma_f32_32x32x16_bf16(                       \
                as_s8(ph0), as_s8(bh0), O, 0, 0, 0);                           \
            O = __builtin_amdgcn_mfma_f32_32x32x16_bf16(                       \
                as_s8(ph0), as_s8(bl0), O, 0, 0, 0);                           \
            O = __builtin_amdgcn_mfma_f32_32x32x16_bf16(                       \
                as_s8(ph1), as_s8(bh1), O, 0, 0, 0);                           \
            O = __builtin_amdgcn_mfma_f32_32x32x16_bf16(                       \
                as_s8(ph1), as_s8(bl1), O, 0, 0, 0);                           \
        }

        for (int c = 0; c < 16; c += 2) {
            ATTN_STEP(Sa, Sb, c, c + 1);
            ATTN_STEP(Sb, Sa, c + 1, (c + 2) & 15);  // last prefetch discarded
        }
#undef ATTN_STEP

        #pragma unroll
        for (int r = 0; r < 16; ++r) {
            float ov = O[r];
            float den = __uint_as_float(
                __builtin_amdgcn_ds_swizzle(__float_as_uint(ov), 0x100));
            float o = ov * fast_rcp(den);
            if (l31 < 8) {
                int row = (r & 3) + 8 * (r >> 2) + 4 * hh;
                obuf[hb + (size_t)(qt * 32 + row) * 8 + l31] = o;
            }
        }
    }
}

// ---------------------------------------------------------------------------
// Kernel 3 (R13, kept): fused projection; Ts padded to 84.
// ---------------------------------------------------------------------------
__global__ __launch_bounds__(128) void proj_kernel(
    const float* __restrict__ obuf,
    const uint4* __restrict__ WfH, const uint4* __restrict__ WfL,
    const float* __restrict__ b10, const float* __restrict__ b11,
    float* __restrict__ out)
{
    __shared__ float Ts[32][84];

    const int tid  = threadIdx.x;
    const int lane = tid & 63;
    const int l31  = lane & 31;
    const int hh   = lane >> 5;
    const int tw   = tid >> 6;               // 0/1: column half this wave owns
    const size_t row = (size_t)blockIdx.x * 32 + l31;
    const size_t blockrow = (size_t)blockIdx.x * 32;

    float16v accM, accC;
    #pragma unroll
    for (int i = 0; i < 16; ++i) { accM[i] = 0.f; accC[i] = 0.f; }

    #pragma unroll
    for (int c = 0; c < 4; ++c) {
        // A-frag cols c*16+hh*8..+7 = head plane 2c+hh, contiguous row.
        const float* ap = obuf + (size_t)(2 * c + hh) * HPLANE + row * 8;
        float av[8];
        {
            float4 a0 = *(const float4*)(ap);
            float4 a1 = *(const float4*)(ap + 4);
            av[0] = a0.x; av[1] = a0.y; av[2] = a0.z; av[3] = a0.w;
            av[4] = a1.x; av[5] = a1.y; av[6] = a1.z; av[7] = a1.w;
        }
        uint4 ahi, alo;
        split_pack8(av, &ahi, &alo);

        const int ei = 3072 + c * 128 + hh * 64 + tw * 32 + l31;   // W10
        const uint4 bh = WfH[ei];
        const uint4 bl = WfL[ei];
        accM = __builtin_amdgcn_mfma_f32_32x32x16_bf16(
            as_s8(ahi), as_s8(bh), accM, 0, 0, 0);
        accC = __builtin_amdgcn_mfma_f32_32x32x16_bf16(
            as_s8(alo), as_s8(bh), accC, 0, 0, 0);
        accC = __builtin_amdgcn_mfma_f32_32x32x16_bf16(
            as_s8(ahi), as_s8(bl), accC, 0, 0, 0);
    }

    {
        const int col = tw * 32 + l31;
        const float bias = b10[col];
        #pragma unroll
        for (int r = 0; r < 16; ++r) {
            const int rowC = (r & 3) + 8 * (r >> 2) + 4 * hh;
            Ts[rowC][col] = fmaxf(accM[r] + accC[r] + bias, 0.f);
        }
    }
    __syncthreads();

    #pragma unroll
    for (int i = 0; i < 16; ++i) { accM[i] = 0.f; accC[i] = 0.f; }

    #pragma unroll
    for (int c = 0; c < 4; ++c) {
        const float* ap = &Ts[l31][c * 16 + hh * 8];
        float av[8];
        {
            float4 a0 = *(const float4*)(ap);
            float4 a1 = *(const float4*)(ap + 4);
            av[0] = a0.x; av[1] = a0.y; av[2] = a0.z; av[3] = a0.w;
            av[4] = a1.x; av[5] = a1.y; av[6] = a1.z; av[7] = a1.w;
        }
        uint4 ahi, alo;
        split_pack8(av, &ahi, &alo);

        const int ei = 3584 + c * 128 + hh * 64 + tw * 32 + l31;   // W11
        const uint4 bh = WfH[ei];
        const uint4 bl = WfL[ei];
        accM = __builtin_amdgcn_mfma_f32_32x32x16_bf16(
            as_s8(ahi), as_s8(bh), accM, 0, 0, 0);
        accC = __builtin_amdgcn_mfma_f32_32x32x16_bf16(
            as_s8(alo), as_s8(bh), accC, 0, 0, 0);
        accC = __builtin_amdgcn_mfma_f32_32x32x16_bf16(
            as_s8(ahi), as_s8(bl), accC, 0, 0, 0);
    }

    {
        const int col = tw * 32 + l31;
        const float bias = b11[col];
        #pragma unroll
        for (int r = 0; r < 16; ++r) {
            const int rowC = (r & 3) + 8 * (r >> 2) + 4 * hh;
            out[(blockrow + rowC) * 64 + col] = accM[r] + accC[r] + bias;
        }
    }
}

// ---------------------------------------------------------------------------
extern "C" void kernel_launch(void* const* d_in, const int* in_sizes, int n_in,
                              void* d_out, int out_size, void* d_ws, size_t ws_size,
                              hipStream_t stream)
{
    const float* X   = (const float*)d_in[0];
    const float* STE = (const float*)d_in[1];
    const float* W7  = (const float*)d_in[2];
    const float* b7  = (const float*)d_in[3];
    const float* W8  = (const float*)d_in[4];
    const float* b8  = (const float*)d_in[5];
    const float* W9  = (const float*)d_in[6];
    const float* b9  = (const float*)d_in[7];
    const float* W10 = (const float*)d_in[8];
    const float* b10 = (const float*)d_in[9];
    const float* W11 = (const float*)d_in[10];
    const float* b11 = (const float*)d_in[11];

    float* ws  = (float*)d_ws;   // Q | K | V | O | Wf
    float* out = (float*)d_out;

    uint4* WfH = (uint4*)(ws + WOFF);
    uint4* WfL = WfH + 4096;

    wprep_kernel<<<dim3(16), 256, 0, stream>>>(W7, W8, W9, W10, W11, WfH, WfL);
    qkv_kernel<<<dim3(RTOT / 32), 384, 0, stream>>>(X, STE, WfH, WfL, b7, b8, b9, ws);
    attn_kernel<<<dim3(BT * 8), 1024, 0, stream>>>(ws, ws + OOFF);
    proj_kernel<<<dim3(RTOT / 32), 128, 0, stream>>>(ws + OOFF, WfH, WfL, b10, b11, out);
}